// Round 10
// baseline (773.660 us; speedup 1.0000x reference)
//
#include <hip/hip_runtime.h>
#include <hip/hip_fp16.h>

#define NUSR 100000
#define NITM 50000
#define NEDG 1000000
#define NPRED 250000
#define DD 64
#define DD2 128
#define MSG_EPS 1e-7f
#define BN_EPS 1e-5f
#define SCAN_B 1024

typedef _Float16 f16x8 __attribute__((ext_vector_type(8)));
typedef float f32x4 __attribute__((ext_vector_type(4)));

// ================= CSR build (once per call; edges are layer-invariant) ==========
// ILP-4: measured faster than ILP-2 despite lower occupancy (round-5 data).

__global__ __launch_bounds__(256) void count_k(
    const int* __restrict__ u_idx, const int* __restrict__ i_idx,
    int* __restrict__ deg_u, int* __restrict__ deg_i)
{
    int base = (blockIdx.x * 256 + threadIdx.x) * 4;
    int u[4], it[4];
    #pragma unroll
    for (int q = 0; q < 4; q++) {
        int e = base + q;
        u[q]  = (e < NEDG) ? u_idx[e] : -1;
        it[q] = (e < NEDG) ? i_idx[e] : -1;
    }
    #pragma unroll
    for (int q = 0; q < 4; q++) if (it[q] >= 0) atomicAdd(&deg_i[it[q]], 1);
    #pragma unroll
    for (int q = 0; q < 4; q++) if (u[q] >= 0) atomicAdd(&deg_u[u[q]], 1);
}

// merged inclusive scan per 1024-chunk for BOTH sides; nbi = item-side block count
__global__ __launch_bounds__(SCAN_B) void scan1_k(
    const int* __restrict__ deg_i, const int* __restrict__ deg_u,
    int* __restrict__ part_i, int* __restrict__ part_u,
    int* __restrict__ bsum_i, int* __restrict__ bsum_u, int nbi)
{
    __shared__ int s[SCAN_B];
    const int* deg; int* partial; int* bsum; int n, bb;
    if ((int)blockIdx.x < nbi) { deg = deg_i; partial = part_i; bsum = bsum_i; n = NITM; bb = blockIdx.x; }
    else { deg = deg_u; partial = part_u; bsum = bsum_u; n = NUSR; bb = blockIdx.x - nbi; }
    int tid = threadIdx.x;
    int i = bb * SCAN_B + tid;
    s[tid] = (i < n) ? deg[i] : 0;
    __syncthreads();
    for (int off = 1; off < SCAN_B; off <<= 1) {
        int t = (tid >= off) ? s[tid - off] : 0;
        __syncthreads();
        s[tid] += t;
        __syncthreads();
    }
    if (i < n) partial[i] = s[tid];
    if (tid == SCAN_B - 1) bsum[bb] = s[tid];
}

__global__ __launch_bounds__(128) void scan2_k(
    int* __restrict__ bsum_i, int* __restrict__ bsum_u, int nbi, int nbu)
{
    __shared__ int s[128];
    int* bsum = (blockIdx.x == 0) ? bsum_i : bsum_u;
    int nb = (blockIdx.x == 0) ? nbi : nbu;
    int tid = threadIdx.x;
    s[tid] = (tid < nb) ? bsum[tid] : 0;
    __syncthreads();
    for (int off = 1; off < 128; off <<= 1) {
        int t = (tid >= off) ? s[tid - off] : 0;
        __syncthreads();
        s[tid] += t;
        __syncthreads();
    }
    if (tid < nb) bsum[tid] = (tid == 0) ? 0 : s[tid - 1];
}

__global__ __launch_bounds__(SCAN_B) void scan3_k(
    const int* __restrict__ deg_i, const int* __restrict__ deg_u,
    const int* __restrict__ part_i, const int* __restrict__ part_u,
    const int* __restrict__ bsum_i, const int* __restrict__ bsum_u,
    int* __restrict__ rowptr_i, int* __restrict__ rowptr_u,
    int* __restrict__ cur_i, int* __restrict__ cur_u, int nbi)
{
    const int* deg; const int* partial; const int* bsum;
    int* rowptr; int* cursor; int n, bb;
    if ((int)blockIdx.x < nbi) {
        deg = deg_i; partial = part_i; bsum = bsum_i;
        rowptr = rowptr_i; cursor = cur_i; n = NITM; bb = blockIdx.x;
    } else {
        deg = deg_u; partial = part_u; bsum = bsum_u;
        rowptr = rowptr_u; cursor = cur_u; n = NUSR; bb = blockIdx.x - nbi;
    }
    int i = bb * SCAN_B + threadIdx.x;
    if (i < n) {
        int rs = partial[i] - deg[i] + bsum[bb];
        rowptr[i] = rs;
        cursor[i] = rs;
    }
    if (i == 0) rowptr[n] = NEDG;
}

__global__ __launch_bounds__(256) void scatter_k(
    const int* __restrict__ u_idx, const int* __restrict__ i_idx,
    int* __restrict__ cur_i, int* __restrict__ cur_u,
    int* __restrict__ csr_i, int* __restrict__ csr_u)
{
    int base = (blockIdx.x * 256 + threadIdx.x) * 4;
    int u[4], it[4], p[4], r[4];
    #pragma unroll
    for (int q = 0; q < 4; q++) {
        int e = base + q;
        u[q]  = (e < NEDG) ? u_idx[e] : -1;
        it[q] = (e < NEDG) ? i_idx[e] : -1;
    }
    #pragma unroll
    for (int q = 0; q < 4; q++) if (it[q] >= 0) p[q] = atomicAdd(&cur_i[it[q]], 1);
    #pragma unroll
    for (int q = 0; q < 4; q++) if (u[q] >= 0) r[q] = atomicAdd(&cur_u[u[q]], 1);
    #pragma unroll
    for (int q = 0; q < 4; q++) if (it[q] >= 0) csr_i[p[q]] = u[q];
    #pragma unroll
    for (int q = 0; q < 4; q++) if (u[q] >= 0) csr_u[r[q]] = it[q];
}

// ========== layer-0 messages for both sides: msg = half(relu(x)+eps) =============
__global__ __launch_bounds__(256) void msg0_k(
    const float* __restrict__ xu, const float* __restrict__ xi,
    __half* __restrict__ msg_u, __half* __restrict__ msg_i)
{
    int i = blockIdx.x * 256 + threadIdx.x;
    const float* x; __half* msg; int idx;
    if (i < NUSR * 16) { x = xu; msg = msg_u; idx = i; }
    else { int j = i - NUSR * 16; if (j >= NITM * 16) return; x = xi; msg = msg_i; idx = j; }
    float4 v = ((const float4*)x)[idx];
    __half2 a = __floats2half2_rn(fmaxf(v.x, 0.f) + MSG_EPS, fmaxf(v.y, 0.f) + MSG_EPS);
    __half2 b = __floats2half2_rn(fmaxf(v.z, 0.f) + MSG_EPS, fmaxf(v.w, 0.f) + MSG_EPS);
    ((__half2*)msg)[idx * 2]     = a;
    ((__half2*)msg)[idx * 2 + 1] = b;
}

// ========== weight convert+transpose to fp16 (once per call) =====================
__global__ __launch_bounds__(256) void wconv_k(
    const float* __restrict__ W1, const float* __restrict__ W2,
    __half* __restrict__ W1t, __half* __restrict__ W2t)
{
    int idx = blockIdx.x * 256 + threadIdx.x;
    if (idx >= 6 * 8192) return;
    int m = idx >> 13, rem = idx & 8191;
    {   // W1 [64][128] -> [128][64]
        int k = rem >> 7, c = rem & 127;
        W1t[m * 8192 + c * 64 + k] = __float2half(W1[idx]);
    }
    {   // W2 [128][64] -> [64][128]
        int k = rem >> 6, c = rem & 63;
        W2t[m * 8192 + c * 128 + k] = __float2half(W2[idx]);
    }
}

// ===== FUSED (item-conv + user-conv) agg + GEMM1 (MFMA fp16) =====================
// no-max softmax (m in [eps,~6], exp safe): den=sum exp, num=sum exp*m, agg=num/den.
// Gather: lane (w,q,ln) owns 4 CONTIGUOUS rows rb..rb+3 (rb=w*16+q*4), processed
// as 2 pairs with fused unroll-4 loops -> 8 loads in flight.
#define EXPUPD(u, dd0,dd1,dd2,dd3, nn0,nn1,nn2,nn3) { \
    float2 va=__half22float2(*(__half2*)&(u).x); \
    float2 vb=__half22float2(*(__half2*)&(u).y); \
    float e0=__expf(va.x), e1=__expf(va.y), e2=__expf(vb.x), e3=__expf(vb.y); \
    dd0+=e0; nn0=fmaf(e0,va.x,nn0); dd1+=e1; nn1=fmaf(e1,va.y,nn1); \
    dd2+=e2; nn2=fmaf(e2,vb.x,nn2); dd3+=e3; nn3=fmaf(e3,vb.y,nn3); }

__global__ __launch_bounds__(256) void aggemm1f_k(
    const __half* __restrict__ msg_i_src, const __half* __restrict__ msg_u_src,
    const float* __restrict__ xi_cur, const float* __restrict__ xu_cur,
    const int* __restrict__ rowptr_i, const int* __restrict__ rowptr_u,
    const int* __restrict__ csr_i, const int* __restrict__ csr_u,
    const __half* __restrict__ W1t_l,   // layer base: [2][128][64] f16
    const float* __restrict__ b1_l,     // [2][128]
    float* __restrict__ h1_i, float* __restrict__ h1_u,
    double* __restrict__ gs_l,          // [2][256] (gsum|gsq per conv)
    int gI)
{
    __shared__ _Float16 sA[64][72];      // 9.2 KB
    __shared__ _Float16 sB[128][72];     // 18.4 KB
    __shared__ float sredS[4][128];      // 2 KB
    __shared__ float sredQ[4][128];      // 2 KB

    int side = ((int)blockIdx.x < gI) ? 0 : 1;
    int bb = side ? (blockIdx.x - gI) : blockIdx.x;
    const __half* msg = side ? msg_i_src : msg_u_src;
    const float* xdst = side ? xu_cur : xi_cur;
    const int* rowptr = side ? rowptr_u : rowptr_i;
    const int* csr    = side ? csr_u : csr_i;
    const __half* W1t = W1t_l + (size_t)side * 8192;
    const float* b1   = b1_l + side * DD2;
    float* h1         = side ? h1_u : h1_i;
    double* gsum      = gs_l + side * 256;
    double* gsq       = gsum + 128;
    int N             = side ? NUSR : NITM;

    int t = threadIdx.x;
    int r0 = bb * 64;
    for (int i = t; i < 1024; i += 256) {
        int row = i >> 3, c8 = i & 7;
        *(float4*)&sB[row][c8 * 8] = ((const float4*)W1t)[i];
    }

    int w = t >> 6, lane = t & 63, q = lane >> 4, ln = lane & 15;
    const uint2* mp = (const uint2*)msg;
    int rb = w * 16 + q * 4;             // 4 contiguous block-local rows

    int begs[4], ends[4];
    #pragma unroll
    for (int ii = 0; ii < 4; ii++) {
        int r = r0 + rb + ii;
        if (r < N) { begs[ii] = rowptr[r]; ends[ii] = rowptr[r + 1]; }
        else { begs[ii] = 0; ends[ii] = 0; }
    }

    #pragma unroll
    for (int pp = 0; pp < 2; pp++) {
        int iiA = pp * 2, iiB = pp * 2 + 1;
        int jA = begs[iiA], eA = ends[iiA];
        int jB = begs[iiB], eB = ends[iiB];
        float dA0=0.f,dA1=0.f,dA2=0.f,dA3=0.f,nA0=0.f,nA1=0.f,nA2=0.f,nA3=0.f;
        float dB0=0.f,dB1=0.f,dB2=0.f,dB3=0.f,nB0=0.f,nB1=0.f,nB2=0.f,nB3=0.f;
        // fused loop: 8 independent gathers in flight
        while (jA + 4 <= eA && jB + 4 <= eB) {
            int a0=csr[jA],a1=csr[jA+1],a2=csr[jA+2],a3=csr[jA+3];
            int b0=csr[jB],b1i=csr[jB+1],b2=csr[jB+2],b3=csr[jB+3];
            uint2 ua0=mp[(size_t)a0*16+ln], ua1=mp[(size_t)a1*16+ln];
            uint2 ua2=mp[(size_t)a2*16+ln], ua3=mp[(size_t)a3*16+ln];
            uint2 ub0=mp[(size_t)b0*16+ln], ub1=mp[(size_t)b1i*16+ln];
            uint2 ub2=mp[(size_t)b2*16+ln], ub3=mp[(size_t)b3*16+ln];
            EXPUPD(ua0, dA0,dA1,dA2,dA3, nA0,nA1,nA2,nA3)
            EXPUPD(ua1, dA0,dA1,dA2,dA3, nA0,nA1,nA2,nA3)
            EXPUPD(ua2, dA0,dA1,dA2,dA3, nA0,nA1,nA2,nA3)
            EXPUPD(ua3, dA0,dA1,dA2,dA3, nA0,nA1,nA2,nA3)
            EXPUPD(ub0, dB0,dB1,dB2,dB3, nB0,nB1,nB2,nB3)
            EXPUPD(ub1, dB0,dB1,dB2,dB3, nB0,nB1,nB2,nB3)
            EXPUPD(ub2, dB0,dB1,dB2,dB3, nB0,nB1,nB2,nB3)
            EXPUPD(ub3, dB0,dB1,dB2,dB3, nB0,nB1,nB2,nB3)
            jA += 4; jB += 4;
        }
        while (jA + 4 <= eA) {
            int a0=csr[jA],a1=csr[jA+1],a2=csr[jA+2],a3=csr[jA+3];
            uint2 ua0=mp[(size_t)a0*16+ln], ua1=mp[(size_t)a1*16+ln];
            uint2 ua2=mp[(size_t)a2*16+ln], ua3=mp[(size_t)a3*16+ln];
            EXPUPD(ua0, dA0,dA1,dA2,dA3, nA0,nA1,nA2,nA3)
            EXPUPD(ua1, dA0,dA1,dA2,dA3, nA0,nA1,nA2,nA3)
            EXPUPD(ua2, dA0,dA1,dA2,dA3, nA0,nA1,nA2,nA3)
            EXPUPD(ua3, dA0,dA1,dA2,dA3, nA0,nA1,nA2,nA3)
            jA += 4;
        }
        while (jB + 4 <= eB) {
            int b0=csr[jB],b1i=csr[jB+1],b2=csr[jB+2],b3=csr[jB+3];
            uint2 ub0=mp[(size_t)b0*16+ln], ub1=mp[(size_t)b1i*16+ln];
            uint2 ub2=mp[(size_t)b2*16+ln], ub3=mp[(size_t)b3*16+ln];
            EXPUPD(ub0, dB0,dB1,dB2,dB3, nB0,nB1,nB2,nB3)
            EXPUPD(ub1, dB0,dB1,dB2,dB3, nB0,nB1,nB2,nB3)
            EXPUPD(ub2, dB0,dB1,dB2,dB3, nB0,nB1,nB2,nB3)
            EXPUPD(ub3, dB0,dB1,dB2,dB3, nB0,nB1,nB2,nB3)
            jB += 4;
        }
        for (; jA < eA; jA++) {
            uint2 u = mp[(size_t)csr[jA]*16+ln];
            EXPUPD(u, dA0,dA1,dA2,dA3, nA0,nA1,nA2,nA3)
        }
        for (; jB < eB; jB++) {
            uint2 u = mp[(size_t)csr[jB]*16+ln];
            EXPUPD(u, dB0,dB1,dB2,dB3, nB0,nB1,nB2,nB3)
        }
        // finalize row A
        {
            int r = r0 + rb + iiA;
            uint2 o = make_uint2(0u, 0u);
            if (r < N) {
                bool nz = ends[iiA] > begs[iiA];
                float g0 = nz ? nA0/dA0 : 0.f;
                float g1 = nz ? nA1/dA1 : 0.f;
                float g2 = nz ? nA2/dA2 : 0.f;
                float g3 = nz ? nA3/dA3 : 0.f;
                float4 xd = ((const float4*)xdst)[(size_t)r*16 + ln];
                __half2 h01 = __floats2half2_rn(g0+xd.x, g1+xd.y);
                __half2 h23 = __floats2half2_rn(g2+xd.z, g3+xd.w);
                o.x = *(unsigned int*)&h01; o.y = *(unsigned int*)&h23;
            }
            *(uint2*)&sA[rb + iiA][ln * 4] = o;
        }
        // finalize row B
        {
            int r = r0 + rb + iiB;
            uint2 o = make_uint2(0u, 0u);
            if (r < N) {
                bool nz = ends[iiB] > begs[iiB];
                float g0 = nz ? nB0/dB0 : 0.f;
                float g1 = nz ? nB1/dB1 : 0.f;
                float g2 = nz ? nB2/dB2 : 0.f;
                float g3 = nz ? nB3/dB3 : 0.f;
                float4 xd = ((const float4*)xdst)[(size_t)r*16 + ln];
                __half2 h01 = __floats2half2_rn(g0+xd.x, g1+xd.y);
                __half2 h23 = __floats2half2_rn(g2+xd.z, g3+xd.w);
                o.x = *(unsigned int*)&h01; o.y = *(unsigned int*)&h23;
            }
            *(uint2*)&sA[rb + iiB][ln * 4] = o;
        }
    }
    __syncthreads();

    f16x8 afr[4][2], bfr[2][2];
    #pragma unroll
    for (int rt = 0; rt < 4; rt++)
        #pragma unroll
        for (int ks = 0; ks < 2; ks++)
            afr[rt][ks] = *(const f16x8*)&sA[rt * 16 + ln][ks * 32 + q * 8];
    #pragma unroll
    for (int ct = 0; ct < 2; ct++)
        #pragma unroll
        for (int ks = 0; ks < 2; ks++)
            bfr[ct][ks] = *(const f16x8*)&sB[w * 32 + ct * 16 + ln][ks * 32 + q * 8];

    f32x4 acc[4][2];
    #pragma unroll
    for (int rt = 0; rt < 4; rt++)
        #pragma unroll
        for (int ct = 0; ct < 2; ct++)
            acc[rt][ct] = (f32x4){0.f, 0.f, 0.f, 0.f};

    #pragma unroll
    for (int rt = 0; rt < 4; rt++)
        #pragma unroll
        for (int ct = 0; ct < 2; ct++) {
            acc[rt][ct] = __builtin_amdgcn_mfma_f32_16x16x32_f16(
                afr[rt][0], bfr[ct][0], acc[rt][ct], 0, 0, 0);
            acc[rt][ct] = __builtin_amdgcn_mfma_f32_16x16x32_f16(
                afr[rt][1], bfr[ct][1], acc[rt][ct], 0, 0, 0);
        }

    float b1c0 = b1[w * 32 + ln];
    float b1c1 = b1[w * 32 + 16 + ln];
    float ps0 = 0.f, pq0 = 0.f, ps1 = 0.f, pq1 = 0.f;
    #pragma unroll
    for (int rt = 0; rt < 4; rt++) {
        #pragma unroll
        for (int i = 0; i < 4; i++) {
            int r = r0 + rt * 16 + q * 4 + i;
            if (r < N) {
                float h0 = acc[rt][0][i] + b1c0;
                float h1v = acc[rt][1][i] + b1c1;
                h1[(size_t)r * DD2 + w * 32 + ln] = h0;
                h1[(size_t)r * DD2 + w * 32 + 16 + ln] = h1v;
                ps0 += h0; pq0 += h0 * h0;
                ps1 += h1v; pq1 += h1v * h1v;
            }
        }
    }
    sredS[q][w * 32 + ln] = ps0;  sredS[q][w * 32 + 16 + ln] = ps1;
    sredQ[q][w * 32 + ln] = pq0;  sredQ[q][w * 32 + 16 + ln] = pq1;
    __syncthreads();
    if (t < 128) {
        float s = 0.f, qq = 0.f;
        #pragma unroll
        for (int k = 0; k < 4; k++) { s += sredS[k][t]; qq += sredQ[k][t]; }
        atomicAdd(&gsum[t], (double)s);
        atomicAdd(&gsq[t],  (double)qq);
    }
}

// ===== FUSED GEMM2 (both convs): xnew = relu(relu(bn(h1)) @ W2 + b2) + msgs ======
__global__ __launch_bounds__(256) void gemm2f_k(
    const float* __restrict__ h1_i, const float* __restrict__ h1_u,
    const double* __restrict__ gs_l,
    const float* __restrict__ gamma_l, const float* __restrict__ beta_l,
    const __half* __restrict__ W2t_l, const float* __restrict__ b2_l,
    float* __restrict__ xi_new, float* __restrict__ xu_new,
    __half* __restrict__ msgi_out, __half* __restrict__ msgu_out, int gI)
{
    __shared__ _Float16 sA[64][136];    // 17.4 KB
    __shared__ _Float16 sB[64][136];    // 17.4 KB
    __shared__ float2 sss[DD2];         // 1 KB

    int side = ((int)blockIdx.x < gI) ? 0 : 1;
    int bb = side ? (blockIdx.x - gI) : blockIdx.x;
    const float* h1   = side ? h1_u : h1_i;
    const double* gsum = gs_l + side * 256;
    const double* gsq  = gsum + 128;
    const float* gamma = gamma_l + side * DD2;
    const float* beta  = beta_l + side * DD2;
    const __half* W2t  = W2t_l + (size_t)side * 8192;
    const float* b2    = b2_l + side * DD;
    float* xnew        = side ? xu_new : xi_new;
    __half* msgout     = side ? msgu_out : msgi_out;
    int N              = side ? NUSR : NITM;

    int t = threadIdx.x;
    if (t < 128) {
        double mean = gsum[t] / (double)N;
        double var  = gsq[t] / (double)N - mean * mean;
        float inv = (float)(1.0 / sqrt(var + (double)BN_EPS));
        float sc = gamma[t] * inv;
        sss[t] = make_float2(sc, beta[t] - (float)mean * sc);
    }
    for (int i = t; i < 1024; i += 256) {
        int row = i >> 4, c8 = i & 15;
        *(float4*)&sB[row][c8 * 8] = ((const float4*)W2t)[i];
    }
    __syncthreads();

    int r0 = bb * 64;
    for (int i = t; i < 2048; i += 256) {
        int rr = i >> 5, c4 = i & 31;
        int r = r0 + rr;
        float4 v = make_float4(0.f, 0.f, 0.f, 0.f);
        if (r < N) {
            v = ((const float4*)h1)[(size_t)r * 32 + c4];
            float2 s0 = sss[c4 * 4], s1 = sss[c4 * 4 + 1];
            float2 s2 = sss[c4 * 4 + 2], s3 = sss[c4 * 4 + 3];
            v.x = fmaxf(fmaf(v.x, s0.x, s0.y), 0.f);
            v.y = fmaxf(fmaf(v.y, s1.x, s1.y), 0.f);
            v.z = fmaxf(fmaf(v.z, s2.x, s2.y), 0.f);
            v.w = fmaxf(fmaf(v.w, s3.x, s3.y), 0.f);
        }
        __half2 a = __floats2half2_rn(v.x, v.y);
        __half2 b = __floats2half2_rn(v.z, v.w);
        uint2 o; o.x = *(unsigned int*)&a; o.y = *(unsigned int*)&b;
        *(uint2*)&sA[rr][c4 * 4] = o;
    }
    __syncthreads();

    int w = t >> 6, lane = t & 63, q = lane >> 4, ln = lane & 15;
    f32x4 acc[4];
    #pragma unroll
    for (int rt = 0; rt < 4; rt++) acc[rt] = (f32x4){0.f, 0.f, 0.f, 0.f};

    #pragma unroll
    for (int ks = 0; ks < 4; ks++) {
        f16x8 bf = *(const f16x8*)&sB[w * 16 + ln][ks * 32 + q * 8];
        #pragma unroll
        for (int rt = 0; rt < 4; rt++) {
            f16x8 af = *(const f16x8*)&sA[rt * 16 + ln][ks * 32 + q * 8];
            acc[rt] = __builtin_amdgcn_mfma_f32_16x16x32_f16(af, bf, acc[rt], 0, 0, 0);
        }
    }

    int c = w * 16 + ln;
    float bb2 = b2[c];
    #pragma unroll
    for (int rt = 0; rt < 4; rt++) {
        #pragma unroll
        for (int i = 0; i < 4; i++) {
            int r = r0 + rt * 16 + q * 4 + i;
            if (r < N) {
                float o = fmaxf(acc[rt][i] + bb2, 0.f);
                xnew[(size_t)r * DD + c] = o;
                msgout[(size_t)r * DD + c] = __float2half(o + MSG_EPS);
            }
        }
    }
}

// ================= decoder ========================================================
__global__ __launch_bounds__(256) void decode_k(
    const float* __restrict__ xu, const float* __restrict__ xi,
    const int* __restrict__ pu, const int* __restrict__ pi,
    float* __restrict__ out)
{
    int idx = blockIdx.x * 256 + threadIdx.x;
    int b = idx >> 4, lane = idx & 15;
    if (b >= NPRED) return;
    int u = pu[b], it = pi[b];
    float4 a = ((const float4*)(xu + (size_t)u * DD))[lane];
    float4 c = ((const float4*)(xi + (size_t)it * DD))[lane];
    float s = a.x * c.x + a.y * c.y + a.z * c.z + a.w * c.w;
    #pragma unroll
    for (int off = 8; off; off >>= 1) s += __shfl_down(s, off, 16);
    if (lane == 0) out[b] = s;
}

extern "C" void kernel_launch(void* const* d_in, const int* in_sizes, int n_in,
                              void* d_out, int out_size, void* d_ws, size_t ws_size,
                              hipStream_t stream)
{
    const float* x_user = (const float*)d_in[0];
    const float* x_item = (const float*)d_in[1];
    const float* W1    = (const float*)d_in[2];   // [3][2][64][128]
    const float* b1    = (const float*)d_in[3];
    const float* gamma = (const float*)d_in[4];
    const float* beta  = (const float*)d_in[5];
    const float* W2    = (const float*)d_in[6];   // [3][2][128][64]
    const float* b2    = (const float*)d_in[7];
    const int* edge = (const int*)d_in[8];        // [2][E]
    const int* pred = (const int*)d_in[9];        // [2][B]
    float* out = (float*)d_out;

    const int* u_idx = edge;
    const int* i_idx = edge + NEDG;

    // ---- workspace bump allocator (256B aligned chunks) ----
    char* p = (char*)d_ws;
    #define ALLOC(ptr, type, count) \
        type* ptr = (type*)p; p += (((size_t)(count) * sizeof(type)) + 255) & ~(size_t)255;

    ALLOC(deg_i, int, NITM)
    ALLOC(deg_u, int, NUSR)
    ALLOC(gsumAll, double, 12 * 256)             // 6 convs x (gsum[128]|gsq[128])
    size_t zero_span = (char*)p - (char*)deg_i;
    ALLOC(part_i, int, NITM)
    ALLOC(part_u, int, NUSR)
    ALLOC(bsum_i, int, 128)
    ALLOC(bsum_u, int, 128)
    ALLOC(rowptr_i, int, NITM + 1)
    ALLOC(rowptr_u, int, NUSR + 1)
    ALLOC(cur_i, int, NITM)
    ALLOC(cur_u, int, NUSR)
    ALLOC(csr_i, int, NEDG)
    ALLOC(csr_u, int, NEDG)
    ALLOC(h1_i, float, (size_t)NITM * DD2)
    ALLOC(h1_u, float, (size_t)NUSR * DD2)
    ALLOC(W1t, __half, 6 * 8192)
    ALLOC(W2t, __half, 6 * 8192)
    ALLOC(xu0, float, (size_t)NUSR * DD)
    ALLOC(xu1, float, (size_t)NUSR * DD)
    ALLOC(xi0, float, (size_t)NITM * DD)
    ALLOC(xi1, float, (size_t)NITM * DD)
    ALLOC(msg_u, __half, (size_t)NUSR * DD)
    ALLOC(msg_i0, __half, (size_t)NITM * DD)
    ALLOC(msg_i1, __half, (size_t)NITM * DD)
    #undef ALLOC
    float* xu_buf[2] = {xu0, xu1};
    float* xi_buf[2] = {xi0, xi1};

    // ---- CSR build + converts (once; reused by all 3 layers) ----
    hipMemsetAsync(deg_i, 0, zero_span, stream);
    int eb4 = (NEDG / 4 + 255) / 256;
    count_k<<<eb4, 256, 0, stream>>>(u_idx, i_idx, deg_u, deg_i);

    int nbi = (NITM + SCAN_B - 1) / SCAN_B;   // 49
    int nbu = (NUSR + SCAN_B - 1) / SCAN_B;   // 98
    scan1_k<<<nbi + nbu, SCAN_B, 0, stream>>>(deg_i, deg_u, part_i, part_u,
                                              bsum_i, bsum_u, nbi);
    scan2_k<<<2, 128, 0, stream>>>(bsum_i, bsum_u, nbi, nbu);
    scan3_k<<<nbi + nbu, SCAN_B, 0, stream>>>(deg_i, deg_u, part_i, part_u,
                                              bsum_i, bsum_u, rowptr_i, rowptr_u,
                                              cur_i, cur_u, nbi);
    scatter_k<<<eb4, 256, 0, stream>>>(u_idx, i_idx, cur_i, cur_u, csr_i, csr_u);

    wconv_k<<<(6 * 8192 + 255) / 256, 256, 0, stream>>>(W1, W2, W1t, W2t);
    msg0_k<<<((NUSR + NITM) * 16 + 255) / 256, 256, 0, stream>>>(x_user, x_item,
                                                                 msg_u, msg_i0);

    // ---- 3 layers, each = 1 fused aggemm1 + 1 fused gemm2 ----
    int gI = (NITM + 63) / 64;    // 782 item blocks
    int gU = (NUSR + 63) / 64;    // 1563 user blocks
    const float* cu = x_user;
    const float* ci = x_item;
    __half* msgi = msg_i0;
    __half* msgi_alt = msg_i1;
    for (int l = 0; l < 3; l++) {
        float* ni = xi_buf[l & 1];
        float* nu = xu_buf[l & 1];
        aggemm1f_k<<<gI + gU, 256, 0, stream>>>(
            msgi, msg_u, ci, cu, rowptr_i, rowptr_u, csr_i, csr_u,
            W1t + (size_t)l * 2 * 8192, b1 + (size_t)l * 2 * DD2,
            h1_i, h1_u, gsumAll + l * 2 * 256, gI);
        gemm2f_k<<<gI + gU, 256, 0, stream>>>(
            h1_i, h1_u, gsumAll + l * 2 * 256,
            gamma + (size_t)l * 2 * DD2, beta + (size_t)l * 2 * DD2,
            W2t + (size_t)l * 2 * 8192, b2 + (size_t)l * 2 * DD,
            ni, nu, msgi_alt, msg_u, gI);
        cu = nu; ci = ni;
        __half* tmp = msgi; msgi = msgi_alt; msgi_alt = tmp;
    }

    decode_k<<<(NPRED * 16) / 256, 256, 0, stream>>>(cu, ci, pred, pred + NPRED, out);
}

// Round 11
// 691.901 us; speedup vs baseline: 1.1182x; 1.1182x over previous
//
#include <hip/hip_runtime.h>
#include <hip/hip_fp16.h>

#define NUSR 100000
#define NITM 50000
#define NEDG 1000000
#define NPRED 250000
#define DD 64
#define DD2 128
#define MSG_EPS 1e-7f
#define BN_EPS 1e-5f
#define SCAN_B 1024

typedef _Float16 f16x8 __attribute__((ext_vector_type(8)));
typedef float f32x4 __attribute__((ext_vector_type(4)));

// ================= CSR build (once per call; edges are layer-invariant) ==========
// ILP-4: measured faster than ILP-2 (R5: 124-135us vs R7-9: 141-153us).

__global__ __launch_bounds__(256) void count_k(
    const int* __restrict__ u_idx, const int* __restrict__ i_idx,
    int* __restrict__ deg_u, int* __restrict__ deg_i)
{
    int base = (blockIdx.x * 256 + threadIdx.x) * 4;
    int u[4], it[4];
    #pragma unroll
    for (int q = 0; q < 4; q++) {
        int e = base + q;
        u[q]  = (e < NEDG) ? u_idx[e] : -1;
        it[q] = (e < NEDG) ? i_idx[e] : -1;
    }
    #pragma unroll
    for (int q = 0; q < 4; q++) if (it[q] >= 0) atomicAdd(&deg_i[it[q]], 1);
    #pragma unroll
    for (int q = 0; q < 4; q++) if (u[q] >= 0) atomicAdd(&deg_u[u[q]], 1);
}

__global__ __launch_bounds__(SCAN_B) void scan1_k(
    const int* __restrict__ deg_i, const int* __restrict__ deg_u,
    int* __restrict__ part_i, int* __restrict__ part_u,
    int* __restrict__ bsum_i, int* __restrict__ bsum_u, int nbi)
{
    __shared__ int s[SCAN_B];
    const int* deg; int* partial; int* bsum; int n, bb;
    if ((int)blockIdx.x < nbi) { deg = deg_i; partial = part_i; bsum = bsum_i; n = NITM; bb = blockIdx.x; }
    else { deg = deg_u; partial = part_u; bsum = bsum_u; n = NUSR; bb = blockIdx.x - nbi; }
    int tid = threadIdx.x;
    int i = bb * SCAN_B + tid;
    s[tid] = (i < n) ? deg[i] : 0;
    __syncthreads();
    for (int off = 1; off < SCAN_B; off <<= 1) {
        int t = (tid >= off) ? s[tid - off] : 0;
        __syncthreads();
        s[tid] += t;
        __syncthreads();
    }
    if (i < n) partial[i] = s[tid];
    if (tid == SCAN_B - 1) bsum[bb] = s[tid];
}

__global__ __launch_bounds__(128) void scan2_k(
    int* __restrict__ bsum_i, int* __restrict__ bsum_u, int nbi, int nbu)
{
    __shared__ int s[128];
    int* bsum = (blockIdx.x == 0) ? bsum_i : bsum_u;
    int nb = (blockIdx.x == 0) ? nbi : nbu;
    int tid = threadIdx.x;
    s[tid] = (tid < nb) ? bsum[tid] : 0;
    __syncthreads();
    for (int off = 1; off < 128; off <<= 1) {
        int t = (tid >= off) ? s[tid - off] : 0;
        __syncthreads();
        s[tid] += t;
        __syncthreads();
    }
    if (tid < nb) bsum[tid] = (tid == 0) ? 0 : s[tid - 1];
}

__global__ __launch_bounds__(SCAN_B) void scan3_k(
    const int* __restrict__ deg_i, const int* __restrict__ deg_u,
    const int* __restrict__ part_i, const int* __restrict__ part_u,
    const int* __restrict__ bsum_i, const int* __restrict__ bsum_u,
    int* __restrict__ rowptr_i, int* __restrict__ rowptr_u,
    int* __restrict__ cur_i, int* __restrict__ cur_u, int nbi)
{
    const int* deg; const int* partial; const int* bsum;
    int* rowptr; int* cursor; int n, bb;
    if ((int)blockIdx.x < nbi) {
        deg = deg_i; partial = part_i; bsum = bsum_i;
        rowptr = rowptr_i; cursor = cur_i; n = NITM; bb = blockIdx.x;
    } else {
        deg = deg_u; partial = part_u; bsum = bsum_u;
        rowptr = rowptr_u; cursor = cur_u; n = NUSR; bb = blockIdx.x - nbi;
    }
    int i = bb * SCAN_B + threadIdx.x;
    if (i < n) {
        int rs = partial[i] - deg[i] + bsum[bb];
        rowptr[i] = rs;
        cursor[i] = rs;
    }
    if (i == 0) rowptr[n] = NEDG;
}

__global__ __launch_bounds__(256) void scatter_k(
    const int* __restrict__ u_idx, const int* __restrict__ i_idx,
    int* __restrict__ cur_i, int* __restrict__ cur_u,
    int* __restrict__ csr_i, int* __restrict__ csr_u)
{
    int base = (blockIdx.x * 256 + threadIdx.x) * 4;
    int u[4], it[4], p[4], r[4];
    #pragma unroll
    for (int q = 0; q < 4; q++) {
        int e = base + q;
        u[q]  = (e < NEDG) ? u_idx[e] : -1;
        it[q] = (e < NEDG) ? i_idx[e] : -1;
    }
    #pragma unroll
    for (int q = 0; q < 4; q++) if (it[q] >= 0) p[q] = atomicAdd(&cur_i[it[q]], 1);
    #pragma unroll
    for (int q = 0; q < 4; q++) if (u[q] >= 0) r[q] = atomicAdd(&cur_u[u[q]], 1);
    #pragma unroll
    for (int q = 0; q < 4; q++) if (it[q] >= 0) csr_i[p[q]] = u[q];
    #pragma unroll
    for (int q = 0; q < 4; q++) if (u[q] >= 0) csr_u[r[q]] = it[q];
}

// ========== layer-0 messages for both sides: msg = half(relu(x)+eps) =============
__global__ __launch_bounds__(256) void msg0_k(
    const float* __restrict__ xu, const float* __restrict__ xi,
    __half* __restrict__ msg_u, __half* __restrict__ msg_i)
{
    int i = blockIdx.x * 256 + threadIdx.x;
    const float* x; __half* msg; int idx;
    if (i < NUSR * 16) { x = xu; msg = msg_u; idx = i; }
    else { int j = i - NUSR * 16; if (j >= NITM * 16) return; x = xi; msg = msg_i; idx = j; }
    float4 v = ((const float4*)x)[idx];
    __half2 a = __floats2half2_rn(fmaxf(v.x, 0.f) + MSG_EPS, fmaxf(v.y, 0.f) + MSG_EPS);
    __half2 b = __floats2half2_rn(fmaxf(v.z, 0.f) + MSG_EPS, fmaxf(v.w, 0.f) + MSG_EPS);
    ((__half2*)msg)[idx * 2]     = a;
    ((__half2*)msg)[idx * 2 + 1] = b;
}

// ========== weight convert+transpose to fp16 (once per call) =====================
__global__ __launch_bounds__(256) void wconv_k(
    const float* __restrict__ W1, const float* __restrict__ W2,
    __half* __restrict__ W1t, __half* __restrict__ W2t)
{
    int idx = blockIdx.x * 256 + threadIdx.x;
    if (idx >= 6 * 8192) return;
    int m = idx >> 13, rem = idx & 8191;
    {   // W1 [64][128] -> [128][64]
        int k = rem >> 7, c = rem & 127;
        W1t[m * 8192 + c * 64 + k] = __float2half(W1[idx]);
    }
    {   // W2 [128][64] -> [64][128]
        int k = rem >> 6, c = rem & 63;
        W2t[m * 8192 + c * 128 + k] = __float2half(W2[idx]);
    }
}

// ===== FUSED (item-conv + user-conv) agg + GEMM1 (MFMA fp16) =====================
// no-max softmax (m in [eps,~6], exp safe): den=sum exp, num=sum exp*m, agg=num/den.
// Gather: round-8 form (per-row sequential, unroll-4 = 4 loads in flight).
// R9's 8-deep row-pairing REGRESSED (731->774us, pathological scheduling) — keep this.
#define UPD(u) { float2 va=__half22float2(*(__half2*)&(u).x); \
                 float2 vb=__half22float2(*(__half2*)&(u).y); \
                 float eA=__expf(va.x), eB=__expf(va.y); \
                 float eC=__expf(vb.x), eD=__expf(vb.y); \
                 dA+=eA; nA=fmaf(eA,va.x,nA); dB+=eB; nB=fmaf(eB,va.y,nB); \
                 dC+=eC; nC=fmaf(eC,vb.x,nC); dD+=eD; nD=fmaf(eD,vb.y,nD); }

__global__ __launch_bounds__(256) void aggemm1f_k(
    const __half* __restrict__ msg_i_src, const __half* __restrict__ msg_u_src,
    const float* __restrict__ xi_cur, const float* __restrict__ xu_cur,
    const int* __restrict__ rowptr_i, const int* __restrict__ rowptr_u,
    const int* __restrict__ csr_i, const int* __restrict__ csr_u,
    const __half* __restrict__ W1t_l,   // layer base: [2][128][64] f16
    const float* __restrict__ b1_l,     // [2][128]
    __half* __restrict__ h1_i, __half* __restrict__ h1_u,   // fp16 h1
    double* __restrict__ gs_l,          // [2][256] (gsum|gsq per conv)
    int gI)
{
    __shared__ _Float16 sA[64][72];      // 9.2 KB
    __shared__ _Float16 sB[128][72];     // 18.4 KB
    __shared__ float sredS[4][128];      // 2 KB
    __shared__ float sredQ[4][128];      // 2 KB

    int side = ((int)blockIdx.x < gI) ? 0 : 1;
    int bb = side ? (blockIdx.x - gI) : blockIdx.x;
    const __half* msg = side ? msg_i_src : msg_u_src;
    const float* xdst = side ? xu_cur : xi_cur;
    const int* rowptr = side ? rowptr_u : rowptr_i;
    const int* csr    = side ? csr_u : csr_i;
    const __half* W1t = W1t_l + (size_t)side * 8192;
    const float* b1   = b1_l + side * DD2;
    __half* h1        = side ? h1_u : h1_i;
    double* gsum      = gs_l + side * 256;
    double* gsq       = gsum + 128;
    int N             = side ? NUSR : NITM;

    int t = threadIdx.x;
    int r0 = bb * 64;
    for (int i = t; i < 1024; i += 256) {
        int row = i >> 3, c8 = i & 7;
        *(float4*)&sB[row][c8 * 8] = ((const float4*)W1t)[i];
    }

    int w = t >> 6, lane = t & 63, q = lane >> 4, ln = lane & 15;
    const uint2* mp = (const uint2*)msg;

    // gather + softmax-agg for this block's 64 rows, results into sA
    #pragma unroll
    for (int ii = 0; ii < 4; ii++) {
        int rr = w * 16 + ii * 4 + q;
        int r = r0 + rr;
        uint2 o = make_uint2(0u, 0u);
        if (r < N) {
            int beg = rowptr[r], end = rowptr[r + 1];
            float dA=0.f,dB=0.f,dC=0.f,dD=0.f,nA=0.f,nB=0.f,nC=0.f,nD=0.f;
            int j = beg;
            for (; j + 4 <= end; j += 4) {
                int s0=csr[j], s1=csr[j+1], s2=csr[j+2], s3=csr[j+3];
                uint2 u0 = mp[(size_t)s0*16+ln];
                uint2 u1 = mp[(size_t)s1*16+ln];
                uint2 u2 = mp[(size_t)s2*16+ln];
                uint2 u3 = mp[(size_t)s3*16+ln];
                UPD(u0) UPD(u1) UPD(u2) UPD(u3)
            }
            for (; j < end; j++) {
                uint2 u = mp[(size_t)csr[j]*16+ln];
                UPD(u)
            }
            bool nz = end > beg;
            float aA = nz ? nA/dA : 0.f;
            float aB = nz ? nB/dB : 0.f;
            float aC = nz ? nC/dC : 0.f;
            float aD = nz ? nD/dD : 0.f;
            float4 xd = ((const float4*)xdst)[(size_t)r*16 + ln];
            __half2 h01 = __floats2half2_rn(aA+xd.x, aB+xd.y);
            __half2 h23 = __floats2half2_rn(aC+xd.z, aD+xd.w);
            o.x = *(unsigned int*)&h01; o.y = *(unsigned int*)&h23;
        }
        *(uint2*)&sA[rr][ln * 4] = o;
    }
    __syncthreads();

    f16x8 afr[4][2], bfr[2][2];
    #pragma unroll
    for (int rt = 0; rt < 4; rt++)
        #pragma unroll
        for (int ks = 0; ks < 2; ks++)
            afr[rt][ks] = *(const f16x8*)&sA[rt * 16 + ln][ks * 32 + q * 8];
    #pragma unroll
    for (int ct = 0; ct < 2; ct++)
        #pragma unroll
        for (int ks = 0; ks < 2; ks++)
            bfr[ct][ks] = *(const f16x8*)&sB[w * 32 + ct * 16 + ln][ks * 32 + q * 8];

    f32x4 acc[4][2];
    #pragma unroll
    for (int rt = 0; rt < 4; rt++)
        #pragma unroll
        for (int ct = 0; ct < 2; ct++)
            acc[rt][ct] = (f32x4){0.f, 0.f, 0.f, 0.f};

    #pragma unroll
    for (int rt = 0; rt < 4; rt++)
        #pragma unroll
        for (int ct = 0; ct < 2; ct++) {
            acc[rt][ct] = __builtin_amdgcn_mfma_f32_16x16x32_f16(
                afr[rt][0], bfr[ct][0], acc[rt][ct], 0, 0, 0);
            acc[rt][ct] = __builtin_amdgcn_mfma_f32_16x16x32_f16(
                afr[rt][1], bfr[ct][1], acc[rt][ct], 0, 0, 0);
        }

    float b1c0 = b1[w * 32 + ln];
    float b1c1 = b1[w * 32 + 16 + ln];
    float ps0 = 0.f, pq0 = 0.f, ps1 = 0.f, pq1 = 0.f;
    #pragma unroll
    for (int rt = 0; rt < 4; rt++) {
        #pragma unroll
        for (int i = 0; i < 4; i++) {
            int r = r0 + rt * 16 + q * 4 + i;
            if (r < N) {
                float h0 = acc[rt][0][i] + b1c0;
                float h1v = acc[rt][1][i] + b1c1;
                h1[(size_t)r * DD2 + w * 32 + ln] = __float2half(h0);
                h1[(size_t)r * DD2 + w * 32 + 16 + ln] = __float2half(h1v);
                ps0 += h0; pq0 += h0 * h0;
                ps1 += h1v; pq1 += h1v * h1v;
            }
        }
    }
    sredS[q][w * 32 + ln] = ps0;  sredS[q][w * 32 + 16 + ln] = ps1;
    sredQ[q][w * 32 + ln] = pq0;  sredQ[q][w * 32 + 16 + ln] = pq1;
    __syncthreads();
    if (t < 128) {
        float s = 0.f, qq = 0.f;
        #pragma unroll
        for (int k = 0; k < 4; k++) { s += sredS[k][t]; qq += sredQ[k][t]; }
        atomicAdd(&gsum[t], (double)s);
        atomicAdd(&gsq[t],  (double)qq);
    }
}

// ===== FUSED GEMM2 (both convs): xnew = relu(relu(bn(h1)) @ W2 + b2) + msgs ======
__global__ __launch_bounds__(256) void gemm2f_k(
    const __half* __restrict__ h1_i, const __half* __restrict__ h1_u,
    const double* __restrict__ gs_l,
    const float* __restrict__ gamma_l, const float* __restrict__ beta_l,
    const __half* __restrict__ W2t_l, const float* __restrict__ b2_l,
    float* __restrict__ xi_new, float* __restrict__ xu_new,
    __half* __restrict__ msgi_out, __half* __restrict__ msgu_out, int gI)
{
    __shared__ _Float16 sA[64][136];    // 17.4 KB
    __shared__ _Float16 sB[64][136];    // 17.4 KB
    __shared__ float2 sss[DD2];         // 1 KB

    int side = ((int)blockIdx.x < gI) ? 0 : 1;
    int bb = side ? (blockIdx.x - gI) : blockIdx.x;
    const __half* h1   = side ? h1_u : h1_i;
    const double* gsum = gs_l + side * 256;
    const double* gsq  = gsum + 128;
    const float* gamma = gamma_l + side * DD2;
    const float* beta  = beta_l + side * DD2;
    const __half* W2t  = W2t_l + (size_t)side * 8192;
    const float* b2    = b2_l + side * DD;
    float* xnew        = side ? xu_new : xi_new;
    __half* msgout     = side ? msgu_out : msgi_out;
    int N              = side ? NUSR : NITM;

    int t = threadIdx.x;
    if (t < 128) {
        double mean = gsum[t] / (double)N;
        double var  = gsq[t] / (double)N - mean * mean;
        float inv = (float)(1.0 / sqrt(var + (double)BN_EPS));
        float sc = gamma[t] * inv;
        sss[t] = make_float2(sc, beta[t] - (float)mean * sc);
    }
    for (int i = t; i < 1024; i += 256) {
        int row = i >> 4, c8 = i & 15;
        *(float4*)&sB[row][c8 * 8] = ((const float4*)W2t)[i];
    }
    __syncthreads();

    int r0 = bb * 64;
    // stage h1 (fp16) with BN + relu -> fp16: 64 rows x 32 uint2 (4 halves each)
    for (int i = t; i < 2048; i += 256) {
        int rr = i >> 5, c4 = i & 31;
        int r = r0 + rr;
        uint2 o = make_uint2(0u, 0u);
        if (r < N) {
            uint2 hv = ((const uint2*)h1)[(size_t)r * 32 + c4];
            float2 va = __half22float2(*(__half2*)&hv.x);
            float2 vb = __half22float2(*(__half2*)&hv.y);
            float2 s0 = sss[c4 * 4], s1 = sss[c4 * 4 + 1];
            float2 s2 = sss[c4 * 4 + 2], s3 = sss[c4 * 4 + 3];
            va.x = fmaxf(fmaf(va.x, s0.x, s0.y), 0.f);
            va.y = fmaxf(fmaf(va.y, s1.x, s1.y), 0.f);
            vb.x = fmaxf(fmaf(vb.x, s2.x, s2.y), 0.f);
            vb.y = fmaxf(fmaf(vb.y, s3.x, s3.y), 0.f);
            __half2 a = __floats2half2_rn(va.x, va.y);
            __half2 b = __floats2half2_rn(vb.x, vb.y);
            o.x = *(unsigned int*)&a; o.y = *(unsigned int*)&b;
        }
        *(uint2*)&sA[rr][c4 * 4] = o;
    }
    __syncthreads();

    int w = t >> 6, lane = t & 63, q = lane >> 4, ln = lane & 15;
    f32x4 acc[4];
    #pragma unroll
    for (int rt = 0; rt < 4; rt++) acc[rt] = (f32x4){0.f, 0.f, 0.f, 0.f};

    #pragma unroll
    for (int ks = 0; ks < 4; ks++) {
        f16x8 bf = *(const f16x8*)&sB[w * 16 + ln][ks * 32 + q * 8];
        #pragma unroll
        for (int rt = 0; rt < 4; rt++) {
            f16x8 af = *(const f16x8*)&sA[rt * 16 + ln][ks * 32 + q * 8];
            acc[rt] = __builtin_amdgcn_mfma_f32_16x16x32_f16(af, bf, acc[rt], 0, 0, 0);
        }
    }

    int c = w * 16 + ln;
    float bb2 = b2[c];
    #pragma unroll
    for (int rt = 0; rt < 4; rt++) {
        #pragma unroll
        for (int i = 0; i < 4; i++) {
            int r = r0 + rt * 16 + q * 4 + i;
            if (r < N) {
                float o = fmaxf(acc[rt][i] + bb2, 0.f);
                xnew[(size_t)r * DD + c] = o;
                msgout[(size_t)r * DD + c] = __float2half(o + MSG_EPS);
            }
        }
    }
}

// ================= decoder ========================================================
__global__ __launch_bounds__(256) void decode_k(
    const float* __restrict__ xu, const float* __restrict__ xi,
    const int* __restrict__ pu, const int* __restrict__ pi,
    float* __restrict__ out)
{
    int idx = blockIdx.x * 256 + threadIdx.x;
    int b = idx >> 4, lane = idx & 15;
    if (b >= NPRED) return;
    int u = pu[b], it = pi[b];
    float4 a = ((const float4*)(xu + (size_t)u * DD))[lane];
    float4 c = ((const float4*)(xi + (size_t)it * DD))[lane];
    float s = a.x * c.x + a.y * c.y + a.z * c.z + a.w * c.w;
    #pragma unroll
    for (int off = 8; off; off >>= 1) s += __shfl_down(s, off, 16);
    if (lane == 0) out[b] = s;
}

extern "C" void kernel_launch(void* const* d_in, const int* in_sizes, int n_in,
                              void* d_out, int out_size, void* d_ws, size_t ws_size,
                              hipStream_t stream)
{
    const float* x_user = (const float*)d_in[0];
    const float* x_item = (const float*)d_in[1];
    const float* W1    = (const float*)d_in[2];   // [3][2][64][128]
    const float* b1    = (const float*)d_in[3];
    const float* gamma = (const float*)d_in[4];
    const float* beta  = (const float*)d_in[5];
    const float* W2    = (const float*)d_in[6];   // [3][2][128][64]
    const float* b2    = (const float*)d_in[7];
    const int* edge = (const int*)d_in[8];        // [2][E]
    const int* pred = (const int*)d_in[9];        // [2][B]
    float* out = (float*)d_out;

    const int* u_idx = edge;
    const int* i_idx = edge + NEDG;

    // ---- workspace bump allocator (256B aligned chunks) ----
    char* p = (char*)d_ws;
    #define ALLOC(ptr, type, count) \
        type* ptr = (type*)p; p += (((size_t)(count) * sizeof(type)) + 255) & ~(size_t)255;

    ALLOC(deg_i, int, NITM)
    ALLOC(deg_u, int, NUSR)
    ALLOC(gsumAll, double, 12 * 256)             // 6 convs x (gsum[128]|gsq[128])
    size_t zero_span = (char*)p - (char*)deg_i;
    ALLOC(part_i, int, NITM)
    ALLOC(part_u, int, NUSR)
    ALLOC(bsum_i, int, 128)
    ALLOC(bsum_u, int, 128)
    ALLOC(rowptr_i, int, NITM + 1)
    ALLOC(rowptr_u, int, NUSR + 1)
    ALLOC(cur_i, int, NITM)
    ALLOC(cur_u, int, NUSR)
    ALLOC(csr_i, int, NEDG)
    ALLOC(csr_u, int, NEDG)
    ALLOC(h1_i, __half, (size_t)NITM * DD2)
    ALLOC(h1_u, __half, (size_t)NUSR * DD2)
    ALLOC(W1t, __half, 6 * 8192)
    ALLOC(W2t, __half, 6 * 8192)
    ALLOC(xu0, float, (size_t)NUSR * DD)
    ALLOC(xu1, float, (size_t)NUSR * DD)
    ALLOC(xi0, float, (size_t)NITM * DD)
    ALLOC(xi1, float, (size_t)NITM * DD)
    ALLOC(msg_u, __half, (size_t)NUSR * DD)
    ALLOC(msg_i0, __half, (size_t)NITM * DD)
    ALLOC(msg_i1, __half, (size_t)NITM * DD)
    #undef ALLOC
    float* xu_buf[2] = {xu0, xu1};
    float* xi_buf[2] = {xi0, xi1};

    // ---- CSR build + converts (once; reused by all 3 layers) ----
    hipMemsetAsync(deg_i, 0, zero_span, stream);
    int eb4 = (NEDG / 4 + 255) / 256;
    count_k<<<eb4, 256, 0, stream>>>(u_idx, i_idx, deg_u, deg_i);

    int nbi = (NITM + SCAN_B - 1) / SCAN_B;   // 49
    int nbu = (NUSR + SCAN_B - 1) / SCAN_B;   // 98
    scan1_k<<<nbi + nbu, SCAN_B, 0, stream>>>(deg_i, deg_u, part_i, part_u,
                                              bsum_i, bsum_u, nbi);
    scan2_k<<<2, 128, 0, stream>>>(bsum_i, bsum_u, nbi, nbu);
    scan3_k<<<nbi + nbu, SCAN_B, 0, stream>>>(deg_i, deg_u, part_i, part_u,
                                              bsum_i, bsum_u, rowptr_i, rowptr_u,
                                              cur_i, cur_u, nbi);
    scatter_k<<<eb4, 256, 0, stream>>>(u_idx, i_idx, cur_i, cur_u, csr_i, csr_u);

    wconv_k<<<(6 * 8192 + 255) / 256, 256, 0, stream>>>(W1, W2, W1t, W2t);
    msg0_k<<<((NUSR + NITM) * 16 + 255) / 256, 256, 0, stream>>>(x_user, x_item,
                                                                 msg_u, msg_i0);

    // ---- 3 layers, each = 1 fused aggemm1 + 1 fused gemm2 ----
    int gI = (NITM + 63) / 64;    // 782 item blocks
    int gU = (NUSR + 63) / 64;    // 1563 user blocks
    const float* cu = x_user;
    const float* ci = x_item;
    __half* msgi = msg_i0;
    __half* msgi_alt = msg_i1;
    for (int l = 0; l < 3; l++) {
        float* ni = xi_buf[l & 1];
        float* nu = xu_buf[l & 1];
        aggemm1f_k<<<gI + gU, 256, 0, stream>>>(
            msgi, msg_u, ci, cu, rowptr_i, rowptr_u, csr_i, csr_u,
            W1t + (size_t)l * 2 * 8192, b1 + (size_t)l * 2 * DD2,
            h1_i, h1_u, gsumAll + l * 2 * 256, gI);
        gemm2f_k<<<gI + gU, 256, 0, stream>>>(
            h1_i, h1_u, gsumAll + l * 2 * 256,
            gamma + (size_t)l * 2 * DD2, beta + (size_t)l * 2 * DD2,
            W2t + (size_t)l * 2 * 8192, b2 + (size_t)l * 2 * DD,
            ni, nu, msgi_alt, msg_u, gI);
        cu = nu; ci = ni;
        __half* tmp = msgi; msgi = msgi_alt; msgi_alt = tmp;
    }

    decode_k<<<(NPRED * 16) / 256, 256, 0, stream>>>(cu, ci, pred, pred + NPRED, out);
}